// Round 4
// baseline (816.336 us; speedup 1.0000x reference)
//
#include <hip/hip_runtime.h>
#include <hip/hip_bf16.h>

// GNNFeatureExtractor: B=512, N=400 nodes, E_DIM=128, hidden 256.
// Contract (established R0-R3): inputs f32 (edge_index int32), output f32.
#define NB 400
#define BB 512
#define ROWS 32      // rows (n-major) per kB2 block
#define USTR 36      // uT LDS row stride (32 + pad, 16B-aligned rows)

// ---- workspace layout (bytes), total ~17.7 MB ----
static constexpr size_t O_FEAT  = 0;            // f32 [400*512*16]  13,107,200
static constexpr size_t O_XPK   = 13107200;     // f32 [512*16*128]   4,194,304 packed masked x_pre
static constexpr size_t O_STATS = 17301504;     // f32 sum1/sq1/sum2/sq2 [400] each
static constexpr size_t O_AB    = 17307904;     // f32 a1/b1v/a2/b2v [400] each
static constexpr size_t O_CS1   = 17314304;     // f32 cs1[128]
static constexpr size_t O_MCNT  = 17314816;     // int mcount[512]
static constexpr size_t O_MLIST = 17316864;     // int mlist[512*16]
static constexpr size_t O_MDINV = 17349632;     // f32 mdinv[512*16]
static constexpr size_t O_MECNT = 17382400;     // int mecnt[512]
static constexpr size_t O_MEDGE = 17384448;     // int medge[512*64]
static constexpr size_t O_LOCG  = 17515520;     // u8  locg[512*400] (255 = unmasked)

// ---------------- Kernel A: per-batch geometry ----------------
__global__ __launch_bounds__(256) void kA(const float* __restrict__ agvs,
                                          const float* __restrict__ nodes,
                                          const int* __restrict__ ei, int E,
                                          float* __restrict__ feat,
                                          int* __restrict__ mcount, int* __restrict__ mlist,
                                          float* __restrict__ mdinv, int* __restrict__ mecnt,
                                          int* __restrict__ medge,
                                          unsigned char* __restrict__ locg)
{
    __shared__ float nod[2 * NB];
    __shared__ float as_[160];
    __shared__ float fs[NB * 16];
    __shared__ int   idxs[70];
    __shared__ int   m0[NB], m1[NB], deg[NB], loc[NB];
    __shared__ int   ecnt;
    const int b = blockIdx.x, t = threadIdx.x;

    for (int i = t; i < 2 * NB; i += 256) nod[i] = nodes[i];
    for (int i = t; i < 160; i += 256)    as_[i] = agvs[b * 160 + i];
    for (int i = t; i < NB * 16; i += 256) fs[i] = 0.f;
    for (int i = t; i < NB; i += 256) m0[i] = 0;
    __syncthreads();

    // 70 argmins: 7 main pairs (coords 2..15), 63 agv pairs. strict '<' = np.argmin first-min.
    if (t < 70) {
        float cx, cy;
        if (t < 7) { cx = as_[2 + 2 * t]; cy = as_[3 + 2 * t]; }
        else { int a = (t - 7) / 7, k = (t - 7) % 7;
               cx = as_[16 * (a + 1) + 2 + 2 * k]; cy = as_[16 * (a + 1) + 3 + 2 * k]; }
        float bd = 3.4e38f; int bi = 0;
        for (int n = 0; n < NB; n++) {
            float dx = __fsub_rn(cx, nod[2 * n]);
            float dy = __fsub_rn(cy, nod[2 * n + 1]);
            float d  = __fadd_rn(__fmul_rn(dx, dx), __fmul_rn(dy, dy));
            if (d < bd) { bd = d; bi = n; }
        }
        idxs[t] = bi;
    }
    // dist feature (col 14): ||node - main[6:8]||
    for (int n = t; n < NB; n += 256) {
        float dx = __fsub_rn(nod[2 * n],     as_[6]);
        float dy = __fsub_rn(nod[2 * n + 1], as_[7]);
        fs[n * 16 + 14] = __fsqrt_rn(__fadd_rn(__fmul_rn(dx, dx), __fmul_rn(dy, dy)));
    }
    __syncthreads();
    if (t < 70) {
        int col = (t < 7) ? t : 7 + ((t - 7) % 7);
        atomicAdd(&fs[idxs[t] * 16 + col], 1.0f);
    }
    if (t == 0) { m0[idxs[1]] = 1; ecnt = 0; }  // seed coords (4,5) == main pair k=1
    __syncthreads();

    // write feat node-major: feat[(n*512+b)*16 + k]
    for (int i = t; i < NB * 16; i += 256) {
        int n = i >> 4, k = i & 15;
        feat[(size_t)((n << 9) + b) * 16 + k] = fs[i];
    }

    // mask = 2-hop expansion: new[row] |= old[col] per edge
    for (int i = t; i < NB; i += 256) m1[i] = m0[i];
    __syncthreads();
    for (int e = t; e < E; e += 256) { int r = ei[e], c = ei[E + e]; if (m0[c]) m1[r] = 1; }
    __syncthreads();
    for (int i = t; i < NB; i += 256) m0[i] = m1[i];
    __syncthreads();
    for (int e = t; e < E; e += 256) { int r = ei[e], c = ei[E + e]; if (m1[c]) m0[r] = 1; }
    __syncthreads();
    for (int i = t; i < NB; i += 256) deg[i] = m0[i];
    __syncthreads();
    for (int e = t; e < E; e += 256) {
        int r = ei[e], c = ei[E + e];
        if (m0[r] && m0[c]) atomicAdd(&deg[c], 1);
    }
    __syncthreads();
    if (t == 0) {
        int cnt = 0;
        for (int n = 0; n < NB; n++) if (m0[n]) {
            loc[n] = cnt;
            mlist[b * 16 + cnt] = n;
            int d = deg[n]; if (d < 1) d = 1;
            mdinv[b * 16 + cnt] = 1.0f / __fsqrt_rn((float)d);
            cnt++;
        }
        mcount[b] = cnt;
    }
    __syncthreads();
    for (int i = t; i < NB; i += 256)
        locg[(size_t)b * NB + i] = m0[i] ? (unsigned char)loc[i] : (unsigned char)255;
    for (int e = t; e < E; e += 256) {
        int r = ei[e], c = ei[E + e];
        if (m0[r] && m0[c]) {
            int s = atomicAdd(&ecnt, 1);
            if (s < 64) medge[b * 64 + s] = loc[r] | (loc[c] << 8);
        }
    }
    __syncthreads();
    if (t == 0) mecnt[b] = ecnt;
}

// ---------------- Kernel B1: BN1 stats — one block per node ----------------
__global__ __launch_bounds__(256) void kB1(const float* __restrict__ feat,
                                           const float* __restrict__ W0,
                                           const float* __restrict__ b0,
                                           float* __restrict__ sum1, float* __restrict__ sumsq1)
{
    __shared__ float fs[512 * 16];   // 32 KB: all feat rows of this node
    __shared__ float red[8];
    const int n = blockIdx.x, t = threadIdx.x;
    for (int i = t; i < 512 * 16; i += 256) fs[i] = feat[(size_t)n * 8192 + i];
    float w0r[15];
#pragma unroll
    for (int k = 0; k < 15; k++) w0r[k] = W0[k * 256 + t];
    const float bias0 = b0[t];
    __syncthreads();
    float s = 0.f, q = 0.f;
    for (int b = 0; b < 512; b++) {
        float acc = bias0;
#pragma unroll
        for (int k = 0; k < 15; k++) acc = fmaf(fs[b * 16 + k], w0r[k], acc);
        acc = fmaxf(acc, 0.f);
        s += acc; q += acc * acc;
    }
    for (int off = 32; off > 0; off >>= 1) { s += __shfl_down(s, off, 64); q += __shfl_down(q, off, 64); }
    if ((t & 63) == 0) { red[t >> 6] = s; red[4 + (t >> 6)] = q; }
    __syncthreads();
    if (t == 0) {
        sum1[n]   = red[0] + red[1] + red[2] + red[3];
        sumsq1[n] = red[4] + red[5] + red[6] + red[7];
    }
}

// ---------------- Kernel F1: BN1 affine + colsum(W1) ----------------
__global__ __launch_bounds__(512) void kF1(const float* __restrict__ sum1, const float* __restrict__ sumsq1,
                                           const float* __restrict__ g1, const float* __restrict__ be1,
                                           const float* __restrict__ W1,
                                           float* __restrict__ a1, float* __restrict__ b1v,
                                           float* __restrict__ cs1)
{
    const int t = threadIdx.x;
    if (t < NB) {
        const float cnt = 512.f * 256.f;
        float m = sum1[t] / cnt;
        float v = fmaxf(sumsq1[t] / cnt - m * m, 0.f);
        float a = g1[t] / sqrtf(v + 1e-5f);
        a1[t] = a;
        b1v[t] = be1[t] - m * a;
    }
    if (t < 128) {
        float s = 0.f;
        for (int c = 0; c < 256; c++) s += W1[c * 128 + t];
        cs1[t] = s;
    }
}

// ---------------- Kernel B2: u -> u@W1 -> fold BN1 -> relu -> BN2 stats -> masked write ----------------
__global__ __launch_bounds__(256) void kB2(const float* __restrict__ feat,
                                           const float* __restrict__ W0,
                                           const float* __restrict__ b0,
                                           const float* __restrict__ W1,
                                           const float* __restrict__ b1,
                                           const float* __restrict__ a1g, const float* __restrict__ b1vg,
                                           const float* __restrict__ cs1,
                                           const unsigned char* __restrict__ locg,
                                           float* __restrict__ xpk,
                                           float* __restrict__ sum2, float* __restrict__ sumsq2)
{
    __shared__ float fT[ROWS * 16];
    __shared__ float uT[256 * USTR];   // u transposed: uT[c][r]
    __shared__ float wc[32 * 128];     // W1 K-chunk
    __shared__ float red[8];
    const int t = threadIdx.x;
    const size_t r0 = (size_t)blockIdx.x * ROWS;
    const int n = (int)(r0 >> 9);      // 512 rows per node

    for (int i = t; i < ROWS * 16; i += 256) fT[i] = feat[r0 * 16 + i];
    __syncthreads();

    // u for channel c=t over 32 rows
    float w0r[15];
#pragma unroll
    for (int k = 0; k < 15; k++) w0r[k] = W0[k * 256 + t];
    const float bias0 = b0[t];
    for (int r = 0; r < ROWS; r++) {
        float acc = bias0;
#pragma unroll
        for (int k = 0; k < 15; k++) acc = fmaf(fT[r * 16 + k], w0r[k], acc);
        uT[t * USTR + r] = fmaxf(acc, 0.f);
    }

    // y = u @ W1 ; thread owns cols (jp, jp+1), rows rr*8..rr*8+7
    const int jp = (t & 63) * 2, rr = t >> 6;
    float acc[16];
#pragma unroll
    for (int i = 0; i < 16; i++) acc[i] = 0.f;

    for (int cc = 0; cc < 256; cc += 32) {
        __syncthreads();
        for (int i = t; i < 32 * 128; i += 256) wc[i] = W1[cc * 128 + i];
        __syncthreads();
        for (int c = 0; c < 32; c++) {
            const float4* up = (const float4*)&uT[(cc + c) * USTR + rr * 8];
            float4 ua = up[0], ub = up[1];
            float wA = wc[c * 128 + jp], wB = wc[c * 128 + jp + 1];
            acc[0]  = fmaf(ua.x, wA, acc[0]);  acc[1]  = fmaf(ua.x, wB, acc[1]);
            acc[2]  = fmaf(ua.y, wA, acc[2]);  acc[3]  = fmaf(ua.y, wB, acc[3]);
            acc[4]  = fmaf(ua.z, wA, acc[4]);  acc[5]  = fmaf(ua.z, wB, acc[5]);
            acc[6]  = fmaf(ua.w, wA, acc[6]);  acc[7]  = fmaf(ua.w, wB, acc[7]);
            acc[8]  = fmaf(ub.x, wA, acc[8]);  acc[9]  = fmaf(ub.x, wB, acc[9]);
            acc[10] = fmaf(ub.y, wA, acc[10]); acc[11] = fmaf(ub.y, wB, acc[11]);
            acc[12] = fmaf(ub.z, wA, acc[12]); acc[13] = fmaf(ub.z, wB, acc[13]);
            acc[14] = fmaf(ub.w, wA, acc[14]); acc[15] = fmaf(ub.w, wB, acc[15]);
        }
    }

    // epilogue: x_pre = relu(a1*y + b1v*cs1 + b1); BN2 stats; packed masked store
    const float A  = a1g[n];
    const float C0 = b1vg[n] * cs1[jp]     + b1[jp];
    const float C1 = b1vg[n] * cs1[jp + 1] + b1[jp + 1];
    float s = 0.f, q = 0.f;
#pragma unroll
    for (int i = 0; i < 8; i++) {
        int row = rr * 8 + i;
        int b = (int)((r0 + row) & 511);
        float x0 = fmaxf(fmaf(A, acc[2 * i],     C0), 0.f);
        float x1 = fmaxf(fmaf(A, acc[2 * i + 1], C1), 0.f);
        s += x0 + x1; q += x0 * x0 + x1 * x1;
        unsigned char lc = locg[(size_t)b * NB + n];
        if (lc != 255) {
            float2 v = make_float2(x0, x1);
            *(float2*)&xpk[(size_t)((b << 4) + lc) * 128 + jp] = v;
        }
    }
    for (int off = 32; off > 0; off >>= 1) { s += __shfl_down(s, off, 64); q += __shfl_down(q, off, 64); }
    if ((t & 63) == 0) { red[t >> 6] = s; red[4 + (t >> 6)] = q; }
    __syncthreads();
    if (t == 0) {
        atomicAdd(&sum2[n],   red[0] + red[1] + red[2] + red[3]);
        atomicAdd(&sumsq2[n], red[4] + red[5] + red[6] + red[7]);
    }
}

// ---------------- Kernel F2: BN2 affine ----------------
__global__ __launch_bounds__(512) void kF2(const float* __restrict__ sum2, const float* __restrict__ sumsq2,
                                           const float* __restrict__ g2, const float* __restrict__ be2,
                                           float* __restrict__ a2, float* __restrict__ b2v)
{
    const int t = threadIdx.x;
    if (t < NB) {
        const float cnt = 512.f * 128.f;
        float m = sum2[t] / cnt;
        float v = fmaxf(sumsq2[t] / cnt - m * m, 0.f);
        float a = g2[t] / sqrtf(v + 1e-5f);
        a2[t] = a;
        b2v[t] = be2[t] - m * a;
    }
}

// ---------------- Kernel E: masked 2-layer GCN + mean, per batch ----------------
__global__ __launch_bounds__(128) void kE(const float* __restrict__ xpk,
                                          const float* __restrict__ a2, const float* __restrict__ b2v,
                                          const float* __restrict__ Wc,
                                          const float* __restrict__ bc,
                                          const int* __restrict__ mcount, const int* __restrict__ mlist,
                                          const float* __restrict__ mdinv, const int* __restrict__ mecnt,
                                          const int* __restrict__ medge,
                                          float* __restrict__ out)
{
    __shared__ float xs[13 * 128];
    __shared__ float hs[13 * 128];
    __shared__ float dv[13];
    __shared__ int   ml[13];
    __shared__ int   eg[64];
    __shared__ int   Ms, Es;
    const int b = blockIdx.x, j = threadIdx.x;
    if (j == 0) { Ms = mcount[b]; Es = mecnt[b]; }
    __syncthreads();
    const int M = Ms, E2 = (Es > 64) ? 64 : Es;
    if (j < 13) {
        if (j < M) { ml[j] = mlist[b * 16 + j]; dv[j] = mdinv[b * 16 + j]; }
        else dv[j] = 0.f;
    }
    for (int e = j; e < E2; e += 128) eg[e] = medge[b * 64 + e];
    __syncthreads();
    // x = a2*x_pre + b2v at masked nodes
    for (int m = 0; m < 13; m++) {
        float v = 0.f;
        if (m < M) {
            int nn = ml[m];
            v = fmaf(a2[nn], xpk[(size_t)((b << 4) + m) * 128 + j], b2v[nn]);
        }
        xs[m * 128 + j] = v;
    }
    __syncthreads();

    for (int it = 0; it < 2; it++) {
        float acc[13];
#pragma unroll
        for (int m = 0; m < 13; m++) acc[m] = 0.f;
        const float* W = Wc + it * 16384;
        for (int c = 0; c < 128; c++) {
            float w = W[c * 128 + j];
#pragma unroll
            for (int m = 0; m < 13; m++) acc[m] = fmaf(xs[m * 128 + c], w, acc[m]);
        }
        __syncthreads();
#pragma unroll
        for (int m = 0; m < 13; m++) hs[m * 128 + j] = acc[m];
#pragma unroll
        for (int m = 0; m < 13; m++) xs[m * 128 + j] = dv[m] * dv[m] * acc[m];
        for (int e = 0; e < E2; e++) {
            int pr = eg[e] & 255, pc = eg[e] >> 8;
            xs[pc * 128 + j] += dv[pr] * dv[pc] * hs[pr * 128 + j];
        }
        float bcv = bc[it * 128 + j];
        for (int m = 0; m < M; m++) xs[m * 128 + j] += bcv;
        __syncthreads();
    }
    float sall = 0.f;
    for (int m = 0; m < M; m++) sall += xs[m * 128 + j];
    out[b * 128 + j] = sall / (float)M;
}

extern "C" void kernel_launch(void* const* d_in, const int* in_sizes, int n_in,
                              void* d_out, int out_size, void* d_ws, size_t ws_size,
                              hipStream_t stream)
{
    const float* agvs  = (const float*)d_in[0];
    const float* nodes = (const float*)d_in[1];
    const int*   ei    = (const int*)d_in[2];
    const float* W0    = (const float*)d_in[3];
    const float* b0    = (const float*)d_in[4];
    const float* g1    = (const float*)d_in[5];
    const float* be1   = (const float*)d_in[6];
    const float* W1    = (const float*)d_in[7];
    const float* b1    = (const float*)d_in[8];
    const float* g2    = (const float*)d_in[9];
    const float* be2   = (const float*)d_in[10];
    const float* Wc    = (const float*)d_in[11];
    const float* bc    = (const float*)d_in[12];
    const int E = in_sizes[2] / 2;

    char* ws = (char*)d_ws;
    float*          feat   = (float*)(ws + O_FEAT);
    float*          xpk    = (float*)(ws + O_XPK);
    float*          sum1   = (float*)(ws + O_STATS);
    float*          sumsq1 = sum1 + NB;
    float*          sum2   = sum1 + 2 * NB;
    float*          sumsq2 = sum1 + 3 * NB;
    float*          a1     = (float*)(ws + O_AB);
    float*          b1v    = a1 + NB;
    float*          a2     = a1 + 2 * NB;
    float*          b2v    = a1 + 3 * NB;
    float*          cs1    = (float*)(ws + O_CS1);
    int*            mcount = (int*)(ws + O_MCNT);
    int*            mlist  = (int*)(ws + O_MLIST);
    float*          mdinv  = (float*)(ws + O_MDINV);
    int*            mecnt  = (int*)(ws + O_MECNT);
    int*            medge  = (int*)(ws + O_MEDGE);
    unsigned char*  locg   = (unsigned char*)(ws + O_LOCG);

    hipMemsetAsync(ws + O_STATS, 0, 4 * NB * sizeof(float), stream);

    kA<<<BB, 256, 0, stream>>>(agvs, nodes, ei, E, feat, mcount, mlist, mdinv, mecnt, medge, locg);
    kB1<<<NB, 256, 0, stream>>>(feat, W0, b0, sum1, sumsq1);
    kF1<<<1, 512, 0, stream>>>(sum1, sumsq1, g1, be1, W1, a1, b1v, cs1);
    kB2<<<(NB * BB) / ROWS, 256, 0, stream>>>(feat, W0, b0, W1, b1, a1, b1v, cs1, locg,
                                              xpk, sum2, sumsq2);
    kF2<<<1, 512, 0, stream>>>(sum2, sumsq2, g2, be2, a2, b2v);
    kE<<<BB, 128, 0, stream>>>(xpk, a2, b2v, Wc, bc, mcount, mlist, mdinv, mecnt, medge,
                               (float*)d_out);
}

// Round 5
// 430.125 us; speedup vs baseline: 1.8979x; 1.8979x over previous
//
#include <hip/hip_runtime.h>
#include <hip/hip_bf16.h>

// GNNFeatureExtractor: B=512, N=400 nodes, E_DIM=128, hidden 256.
// Contract (established R0-R4): inputs f32 (edge_index int32), output f32.
#define NB 400
#define BB 512
#define ROWS 32      // rows (n-major) per kB2 block
#define USTR 36      // uT LDS row stride (32 + pad, 16B-aligned rows)

// ---- workspace layout (bytes), total ~17.7 MB ----
static constexpr size_t O_FEAT  = 0;            // f32 [400*512*16]  13,107,200
static constexpr size_t O_XPK   = 13107200;     // f32 [512*16*128]   4,194,304 packed masked x_pre
static constexpr size_t O_STATS = 17301504;     // f32 sum1/sq1/sum2/sq2 [400] each
static constexpr size_t O_AB    = 17307904;     // f32 a1/b1v/a2/b2v [400] each
static constexpr size_t O_CS1   = 17314304;     // f32 cs1[128]
static constexpr size_t O_MCNT  = 17314816;     // int mcount[512]
static constexpr size_t O_MLIST = 17316864;     // int mlist[512*16]
static constexpr size_t O_MDINV = 17349632;     // f32 mdinv[512*16]
static constexpr size_t O_MECNT = 17382400;     // int mecnt[512]
static constexpr size_t O_MEDGE = 17384448;     // int medge[512*64]
static constexpr size_t O_LOCG  = 17515520;     // u8  locg[512*400] (255 = unmasked)

// ---------------- Kernel A: per-batch geometry ----------------
__global__ __launch_bounds__(256) void kA(const float* __restrict__ agvs,
                                          const float* __restrict__ nodes,
                                          const int* __restrict__ ei, int E,
                                          float* __restrict__ feat,
                                          int* __restrict__ mcount, int* __restrict__ mlist,
                                          float* __restrict__ mdinv, int* __restrict__ mecnt,
                                          int* __restrict__ medge,
                                          unsigned char* __restrict__ locg)
{
    __shared__ float nod[2 * NB];
    __shared__ float as_[160];
    __shared__ float fs[NB * 16];
    __shared__ int   idxs[70];
    __shared__ int   m0[NB], m1[NB], deg[NB], loc[NB];
    __shared__ int   ecnt;
    const int b = blockIdx.x, t = threadIdx.x;

    for (int i = t; i < 2 * NB; i += 256) nod[i] = nodes[i];
    for (int i = t; i < 160; i += 256)    as_[i] = agvs[b * 160 + i];
    for (int i = t; i < NB * 16; i += 256) fs[i] = 0.f;
    for (int i = t; i < NB; i += 256) m0[i] = 0;
    __syncthreads();

    // 70 argmins: 7 main pairs (coords 2..15), 63 agv pairs. strict '<' = np.argmin first-min.
    if (t < 70) {
        float cx, cy;
        if (t < 7) { cx = as_[2 + 2 * t]; cy = as_[3 + 2 * t]; }
        else { int a = (t - 7) / 7, k = (t - 7) % 7;
               cx = as_[16 * (a + 1) + 2 + 2 * k]; cy = as_[16 * (a + 1) + 3 + 2 * k]; }
        float bd = 3.4e38f; int bi = 0;
        for (int n = 0; n < NB; n++) {
            float dx = __fsub_rn(cx, nod[2 * n]);
            float dy = __fsub_rn(cy, nod[2 * n + 1]);
            float d  = __fadd_rn(__fmul_rn(dx, dx), __fmul_rn(dy, dy));
            if (d < bd) { bd = d; bi = n; }
        }
        idxs[t] = bi;
    }
    // dist feature (col 14): ||node - main[6:8]||
    for (int n = t; n < NB; n += 256) {
        float dx = __fsub_rn(nod[2 * n],     as_[6]);
        float dy = __fsub_rn(nod[2 * n + 1], as_[7]);
        fs[n * 16 + 14] = __fsqrt_rn(__fadd_rn(__fmul_rn(dx, dx), __fmul_rn(dy, dy)));
    }
    __syncthreads();
    if (t < 70) {
        int col = (t < 7) ? t : 7 + ((t - 7) % 7);
        atomicAdd(&fs[idxs[t] * 16 + col], 1.0f);
    }
    if (t == 0) { m0[idxs[1]] = 1; ecnt = 0; }  // seed coords (4,5) == main pair k=1
    __syncthreads();

    // write feat node-major: feat[(n*512+b)*16 + k]
    for (int i = t; i < NB * 16; i += 256) {
        int n = i >> 4, k = i & 15;
        feat[(size_t)((n << 9) + b) * 16 + k] = fs[i];
    }

    // mask = 2-hop expansion: new[row] |= old[col] per edge
    for (int i = t; i < NB; i += 256) m1[i] = m0[i];
    __syncthreads();
    for (int e = t; e < E; e += 256) { int r = ei[e], c = ei[E + e]; if (m0[c]) m1[r] = 1; }
    __syncthreads();
    for (int i = t; i < NB; i += 256) m0[i] = m1[i];
    __syncthreads();
    for (int e = t; e < E; e += 256) { int r = ei[e], c = ei[E + e]; if (m1[c]) m0[r] = 1; }
    __syncthreads();
    for (int i = t; i < NB; i += 256) deg[i] = m0[i];
    __syncthreads();
    for (int e = t; e < E; e += 256) {
        int r = ei[e], c = ei[E + e];
        if (m0[r] && m0[c]) atomicAdd(&deg[c], 1);
    }
    __syncthreads();
    if (t == 0) {
        int cnt = 0;
        for (int n = 0; n < NB; n++) if (m0[n]) {
            loc[n] = cnt;
            mlist[b * 16 + cnt] = n;
            int d = deg[n]; if (d < 1) d = 1;
            mdinv[b * 16 + cnt] = 1.0f / __fsqrt_rn((float)d);
            cnt++;
        }
        mcount[b] = cnt;
    }
    __syncthreads();
    for (int i = t; i < NB; i += 256)
        locg[(size_t)b * NB + i] = m0[i] ? (unsigned char)loc[i] : (unsigned char)255;
    for (int e = t; e < E; e += 256) {
        int r = ei[e], c = ei[E + e];
        if (m0[r] && m0[c]) {
            int s = atomicAdd(&ecnt, 1);
            if (s < 64) medge[b * 64 + s] = loc[r] | (loc[c] << 8);
        }
    }
    __syncthreads();
    if (t == 0) mecnt[b] = ecnt;
}

// ---------------- Kernel B1: BN1 stats — one block per node ----------------
__global__ __launch_bounds__(256) void kB1(const float* __restrict__ feat,
                                           const float* __restrict__ W0,
                                           const float* __restrict__ b0,
                                           float* __restrict__ sum1, float* __restrict__ sumsq1)
{
    __shared__ float fs[512 * 16];   // 32 KB: all feat rows of this node
    __shared__ float red[8];
    const int n = blockIdx.x, t = threadIdx.x;
    for (int i = t; i < 512 * 16; i += 256) fs[i] = feat[(size_t)n * 8192 + i];
    float w0r[15];
#pragma unroll
    for (int k = 0; k < 15; k++) w0r[k] = W0[k * 256 + t];
    const float bias0 = b0[t];
    __syncthreads();
    float s = 0.f, q = 0.f;
    for (int b = 0; b < 512; b++) {
        float acc = bias0;
#pragma unroll
        for (int k = 0; k < 15; k++) acc = fmaf(fs[b * 16 + k], w0r[k], acc);
        acc = fmaxf(acc, 0.f);
        s += acc; q += acc * acc;
    }
    for (int off = 32; off > 0; off >>= 1) { s += __shfl_down(s, off, 64); q += __shfl_down(q, off, 64); }
    if ((t & 63) == 0) { red[t >> 6] = s; red[4 + (t >> 6)] = q; }
    __syncthreads();
    if (t == 0) {
        sum1[n]   = red[0] + red[1] + red[2] + red[3];
        sumsq1[n] = red[4] + red[5] + red[6] + red[7];
    }
}

// ---------------- Kernel F1: BN1 affine + colsum(W1) ----------------
__global__ __launch_bounds__(512) void kF1(const float* __restrict__ sum1, const float* __restrict__ sumsq1,
                                           const float* __restrict__ g1, const float* __restrict__ be1,
                                           const float* __restrict__ W1,
                                           float* __restrict__ a1, float* __restrict__ b1v,
                                           float* __restrict__ cs1)
{
    const int t = threadIdx.x;
    if (t < NB) {
        const float cnt = 512.f * 256.f;
        float m = sum1[t] / cnt;
        float v = fmaxf(sumsq1[t] / cnt - m * m, 0.f);
        float a = g1[t] / sqrtf(v + 1e-5f);
        a1[t] = a;
        b1v[t] = be1[t] - m * a;
    }
    if (t < 128) {
        float s = 0.f;
        for (int c = 0; c < 256; c++) s += W1[c * 128 + t];
        cs1[t] = s;
    }
}

// ---------------- Kernel B2: u -> u@W1 -> fold BN1 -> relu -> BN2 stats -> masked write ----------------
// Occupancy-focused rewrite (R5): no W1 LDS staging (wave-broadcast uT reads are
// LDS-free-ish; W1 rows are L2-resident and read wave-coalesced). LDS ~39 KB ->
// 4 blocks/CU; __launch_bounds__(256,4) caps VGPR<=128 -> 16 waves/CU.
__global__ __launch_bounds__(256, 4) void kB2(const float* __restrict__ feat,
                                           const float* __restrict__ W0,
                                           const float* __restrict__ b0,
                                           const float* __restrict__ W1,
                                           const float* __restrict__ b1,
                                           const float* __restrict__ a1g, const float* __restrict__ b1vg,
                                           const float* __restrict__ cs1,
                                           const unsigned char* __restrict__ locg,
                                           float* __restrict__ xpk,
                                           float* __restrict__ sum2, float* __restrict__ sumsq2)
{
    __shared__ float fT[ROWS * 16];
    __shared__ float uT[256 * USTR];   // u transposed: uT[c][r]
    __shared__ float red[8];
    const int t = threadIdx.x;
    const size_t r0 = (size_t)blockIdx.x * ROWS;
    const int n = (int)(r0 >> 9);      // 512 rows per node

    for (int i = t; i < ROWS * 16; i += 256) fT[i] = feat[r0 * 16 + i];
    __syncthreads();

    // phase 2: u for channel c=t over 32 rows
    {
        float w0r[15];
#pragma unroll
        for (int k = 0; k < 15; k++) w0r[k] = W0[k * 256 + t];
        const float bias0 = b0[t];
        for (int r = 0; r < ROWS; r++) {
            float acc = bias0;
#pragma unroll
            for (int k = 0; k < 15; k++) acc = fmaf(fT[r * 16 + k], w0r[k], acc);
            uT[t * USTR + r] = fmaxf(acc, 0.f);
        }
    }
    __syncthreads();

    // phase 3: y = u @ W1 ; thread owns cols (jp, jp+1), rows rr*8..rr*8+7.
    // uT reads are wave-uniform (rr constant per wave) -> LDS broadcast.
    // W1 read from global: row c, lanes read 2 consecutive floats -> coalesced, L2-hit.
    const int jp = (t & 63) * 2, rr = t >> 6;
    const float* __restrict__ w1p = W1 + jp;
    float acc[16];
#pragma unroll
    for (int i = 0; i < 16; i++) acc[i] = 0.f;

    for (int c = 0; c < 256; c += 4) {
        // issue all 4 W1 loads up front (in-flight overlap)
        float2 wv0 = *(const float2*)&w1p[(c + 0) * 128];
        float2 wv1 = *(const float2*)&w1p[(c + 1) * 128];
        float2 wv2 = *(const float2*)&w1p[(c + 2) * 128];
        float2 wv3 = *(const float2*)&w1p[(c + 3) * 128];
#pragma unroll
        for (int cc = 0; cc < 4; cc++) {
            float2 wv = (cc == 0) ? wv0 : (cc == 1) ? wv1 : (cc == 2) ? wv2 : wv3;
            const float4* up = (const float4*)&uT[(c + cc) * USTR + rr * 8];
            float4 ua = up[0], ub = up[1];
            acc[0]  = fmaf(ua.x, wv.x, acc[0]);  acc[1]  = fmaf(ua.x, wv.y, acc[1]);
            acc[2]  = fmaf(ua.y, wv.x, acc[2]);  acc[3]  = fmaf(ua.y, wv.y, acc[3]);
            acc[4]  = fmaf(ua.z, wv.x, acc[4]);  acc[5]  = fmaf(ua.z, wv.y, acc[5]);
            acc[6]  = fmaf(ua.w, wv.x, acc[6]);  acc[7]  = fmaf(ua.w, wv.y, acc[7]);
            acc[8]  = fmaf(ub.x, wv.x, acc[8]);  acc[9]  = fmaf(ub.x, wv.y, acc[9]);
            acc[10] = fmaf(ub.y, wv.x, acc[10]); acc[11] = fmaf(ub.y, wv.y, acc[11]);
            acc[12] = fmaf(ub.z, wv.x, acc[12]); acc[13] = fmaf(ub.z, wv.y, acc[13]);
            acc[14] = fmaf(ub.w, wv.x, acc[14]); acc[15] = fmaf(ub.w, wv.y, acc[15]);
        }
    }

    // epilogue: x_pre = relu(a1*y + b1v*cs1 + b1); BN2 stats; packed masked store
    const float A  = a1g[n];
    const float C0 = b1vg[n] * cs1[jp]     + b1[jp];
    const float C1 = b1vg[n] * cs1[jp + 1] + b1[jp + 1];
    float s = 0.f, q = 0.f;
#pragma unroll
    for (int i = 0; i < 8; i++) {
        int row = rr * 8 + i;
        int b = (int)((r0 + row) & 511);
        float x0 = fmaxf(fmaf(A, acc[2 * i],     C0), 0.f);
        float x1 = fmaxf(fmaf(A, acc[2 * i + 1], C1), 0.f);
        s += x0 + x1; q += x0 * x0 + x1 * x1;
        unsigned char lc = locg[(size_t)b * NB + n];
        if (lc != 255) {
            float2 v = make_float2(x0, x1);
            *(float2*)&xpk[(size_t)((b << 4) + lc) * 128 + jp] = v;
        }
    }
    for (int off = 32; off > 0; off >>= 1) { s += __shfl_down(s, off, 64); q += __shfl_down(q, off, 64); }
    if ((t & 63) == 0) { red[t >> 6] = s; red[4 + (t >> 6)] = q; }
    __syncthreads();
    if (t == 0) {
        atomicAdd(&sum2[n],   red[0] + red[1] + red[2] + red[3]);
        atomicAdd(&sumsq2[n], red[4] + red[5] + red[6] + red[7]);
    }
}

// ---------------- Kernel F2: BN2 affine ----------------
__global__ __launch_bounds__(512) void kF2(const float* __restrict__ sum2, const float* __restrict__ sumsq2,
                                           const float* __restrict__ g2, const float* __restrict__ be2,
                                           float* __restrict__ a2, float* __restrict__ b2v)
{
    const int t = threadIdx.x;
    if (t < NB) {
        const float cnt = 512.f * 128.f;
        float m = sum2[t] / cnt;
        float v = fmaxf(sumsq2[t] / cnt - m * m, 0.f);
        float a = g2[t] / sqrtf(v + 1e-5f);
        a2[t] = a;
        b2v[t] = be2[t] - m * a;
    }
}

// ---------------- Kernel E: masked 2-layer GCN + mean, per batch ----------------
__global__ __launch_bounds__(128) void kE(const float* __restrict__ xpk,
                                          const float* __restrict__ a2, const float* __restrict__ b2v,
                                          const float* __restrict__ Wc,
                                          const float* __restrict__ bc,
                                          const int* __restrict__ mcount, const int* __restrict__ mlist,
                                          const float* __restrict__ mdinv, const int* __restrict__ mecnt,
                                          const int* __restrict__ medge,
                                          float* __restrict__ out)
{
    __shared__ float xs[13 * 128];
    __shared__ float hs[13 * 128];
    __shared__ float dv[13];
    __shared__ int   ml[13];
    __shared__ int   eg[64];
    __shared__ int   Ms, Es;
    const int b = blockIdx.x, j = threadIdx.x;
    if (j == 0) { Ms = mcount[b]; Es = mecnt[b]; }
    __syncthreads();
    const int M = Ms, E2 = (Es > 64) ? 64 : Es;
    if (j < 13) {
        if (j < M) { ml[j] = mlist[b * 16 + j]; dv[j] = mdinv[b * 16 + j]; }
        else dv[j] = 0.f;
    }
    for (int e = j; e < E2; e += 128) eg[e] = medge[b * 64 + e];
    __syncthreads();
    // x = a2*x_pre + b2v at masked nodes
    for (int m = 0; m < 13; m++) {
        float v = 0.f;
        if (m < M) {
            int nn = ml[m];
            v = fmaf(a2[nn], xpk[(size_t)((b << 4) + m) * 128 + j], b2v[nn]);
        }
        xs[m * 128 + j] = v;
    }
    __syncthreads();

    for (int it = 0; it < 2; it++) {
        float acc[13];
#pragma unroll
        for (int m = 0; m < 13; m++) acc[m] = 0.f;
        const float* W = Wc + it * 16384;
        for (int c = 0; c < 128; c++) {
            float w = W[c * 128 + j];
#pragma unroll
            for (int m = 0; m < 13; m++) acc[m] = fmaf(xs[m * 128 + c], w, acc[m]);
        }
        __syncthreads();
#pragma unroll
        for (int m = 0; m < 13; m++) hs[m * 128 + j] = acc[m];
#pragma unroll
        for (int m = 0; m < 13; m++) xs[m * 128 + j] = dv[m] * dv[m] * acc[m];
        for (int e = 0; e < E2; e++) {
            int pr = eg[e] & 255, pc = eg[e] >> 8;
            xs[pc * 128 + j] += dv[pr] * dv[pc] * hs[pr * 128 + j];
        }
        float bcv = bc[it * 128 + j];
        for (int m = 0; m < M; m++) xs[m * 128 + j] += bcv;
        __syncthreads();
    }
    float sall = 0.f;
    for (int m = 0; m < M; m++) sall += xs[m * 128 + j];
    out[b * 128 + j] = sall / (float)M;
}

extern "C" void kernel_launch(void* const* d_in, const int* in_sizes, int n_in,
                              void* d_out, int out_size, void* d_ws, size_t ws_size,
                              hipStream_t stream)
{
    const float* agvs  = (const float*)d_in[0];
    const float* nodes = (const float*)d_in[1];
    const int*   ei    = (const int*)d_in[2];
    const float* W0    = (const float*)d_in[3];
    const float* b0    = (const float*)d_in[4];
    const float* g1    = (const float*)d_in[5];
    const float* be1   = (const float*)d_in[6];
    const float* W1    = (const float*)d_in[7];
    const float* b1    = (const float*)d_in[8];
    const float* g2    = (const float*)d_in[9];
    const float* be2   = (const float*)d_in[10];
    const float* Wc    = (const float*)d_in[11];
    const float* bc    = (const float*)d_in[12];
    const int E = in_sizes[2] / 2;

    char* ws = (char*)d_ws;
    float*          feat   = (float*)(ws + O_FEAT);
    float*          xpk    = (float*)(ws + O_XPK);
    float*          sum1   = (float*)(ws + O_STATS);
    float*          sumsq1 = sum1 + NB;
    float*          sum2   = sum1 + 2 * NB;
    float*          sumsq2 = sum1 + 3 * NB;
    float*          a1     = (float*)(ws + O_AB);
    float*          b1v    = a1 + NB;
    float*          a2     = a1 + 2 * NB;
    float*          b2v    = a1 + 3 * NB;
    float*          cs1    = (float*)(ws + O_CS1);
    int*            mcount = (int*)(ws + O_MCNT);
    int*            mlist  = (int*)(ws + O_MLIST);
    float*          mdinv  = (float*)(ws + O_MDINV);
    int*            mecnt  = (int*)(ws + O_MECNT);
    int*            medge  = (int*)(ws + O_MEDGE);
    unsigned char*  locg   = (unsigned char*)(ws + O_LOCG);

    hipMemsetAsync(ws + O_STATS, 0, 4 * NB * sizeof(float), stream);

    kA<<<BB, 256, 0, stream>>>(agvs, nodes, ei, E, feat, mcount, mlist, mdinv, mecnt, medge, locg);
    kB1<<<NB, 256, 0, stream>>>(feat, W0, b0, sum1, sumsq1);
    kF1<<<1, 512, 0, stream>>>(sum1, sumsq1, g1, be1, W1, a1, b1v, cs1);
    kB2<<<(NB * BB) / ROWS, 256, 0, stream>>>(feat, W0, b0, W1, b1, a1, b1v, cs1, locg,
                                              xpk, sum2, sumsq2);
    kF2<<<1, 512, 0, stream>>>(sum2, sumsq2, g2, be2, a2, b2v);
    kE<<<BB, 128, 0, stream>>>(xpk, a2, b2v, Wc, bc, mcount, mlist, mdinv, mecnt, medge,
                               (float*)d_out);
}

// Round 6
// 280.381 us; speedup vs baseline: 2.9115x; 1.5341x over previous
//
#include <hip/hip_runtime.h>
#include <hip/hip_bf16.h>

// GNNFeatureExtractor: B=512, N=400 nodes, E_DIM=128, hidden 256.
// Contract (established R0-R4): inputs f32 (edge_index int32), output f32.
#define NB 400
#define BB 512
#define ROWS 32      // rows (n-major) per kB2 block
#define KSTR 264     // uB LDS row stride in bf16 (16B-aligned rows)

typedef short  bf16x8 __attribute__((ext_vector_type(8)));   // 8 bf16 = 4 VGPRs
typedef float  f32x16 __attribute__((ext_vector_type(16)));

// ---- workspace layout (bytes), total ~17.8 MB ----
static constexpr size_t O_FEAT  = 0;            // f32 [400*512*16]  13,107,200
static constexpr size_t O_XPK   = 13107200;     // f32 [512*16*128]   4,194,304 packed masked x_pre
static constexpr size_t O_STATS = 17301504;     // f32 sum1/sq1/sum2/sq2 [400] each
static constexpr size_t O_AB    = 17307904;     // f32 a1/b1v/a2/b2v [400] each
static constexpr size_t O_CS1   = 17314304;     // f32 cs1[128]
static constexpr size_t O_MCNT  = 17314816;     // int mcount[512]
static constexpr size_t O_MLIST = 17316864;     // int mlist[512*16]
static constexpr size_t O_MDINV = 17349632;     // f32 mdinv[512*16]
static constexpr size_t O_MECNT = 17382400;     // int mecnt[512]
static constexpr size_t O_MEDGE = 17384448;     // int medge[512*64]
static constexpr size_t O_LOCG  = 17515520;     // u8  locg[512*400] (255 = unmasked)
static constexpr size_t O_W1T   = 17720320;     // bf16 [128][256] transposed W1, 65,536

// ---------------- Kernel A: per-batch geometry ----------------
__global__ __launch_bounds__(256) void kA(const float* __restrict__ agvs,
                                          const float* __restrict__ nodes,
                                          const int* __restrict__ ei, int E,
                                          float* __restrict__ feat,
                                          int* __restrict__ mcount, int* __restrict__ mlist,
                                          float* __restrict__ mdinv, int* __restrict__ mecnt,
                                          int* __restrict__ medge,
                                          unsigned char* __restrict__ locg)
{
    __shared__ float nod[2 * NB];
    __shared__ float as_[160];
    __shared__ float fs[NB * 16];
    __shared__ int   idxs[70];
    __shared__ int   m0[NB], m1[NB], deg[NB], loc[NB];
    __shared__ int   ecnt;
    const int b = blockIdx.x, t = threadIdx.x;

    for (int i = t; i < 2 * NB; i += 256) nod[i] = nodes[i];
    for (int i = t; i < 160; i += 256)    as_[i] = agvs[b * 160 + i];
    for (int i = t; i < NB * 16; i += 256) fs[i] = 0.f;
    for (int i = t; i < NB; i += 256) m0[i] = 0;
    __syncthreads();

    // 70 argmins: 7 main pairs (coords 2..15), 63 agv pairs. strict '<' = np.argmin first-min.
    if (t < 70) {
        float cx, cy;
        if (t < 7) { cx = as_[2 + 2 * t]; cy = as_[3 + 2 * t]; }
        else { int a = (t - 7) / 7, k = (t - 7) % 7;
               cx = as_[16 * (a + 1) + 2 + 2 * k]; cy = as_[16 * (a + 1) + 3 + 2 * k]; }
        float bd = 3.4e38f; int bi = 0;
        for (int n = 0; n < NB; n++) {
            float dx = __fsub_rn(cx, nod[2 * n]);
            float dy = __fsub_rn(cy, nod[2 * n + 1]);
            float d  = __fadd_rn(__fmul_rn(dx, dx), __fmul_rn(dy, dy));
            if (d < bd) { bd = d; bi = n; }
        }
        idxs[t] = bi;
    }
    // dist feature (col 14): ||node - main[6:8]||
    for (int n = t; n < NB; n += 256) {
        float dx = __fsub_rn(nod[2 * n],     as_[6]);
        float dy = __fsub_rn(nod[2 * n + 1], as_[7]);
        fs[n * 16 + 14] = __fsqrt_rn(__fadd_rn(__fmul_rn(dx, dx), __fmul_rn(dy, dy)));
    }
    __syncthreads();
    if (t < 70) {
        int col = (t < 7) ? t : 7 + ((t - 7) % 7);
        atomicAdd(&fs[idxs[t] * 16 + col], 1.0f);
    }
    if (t == 0) { m0[idxs[1]] = 1; ecnt = 0; }  // seed coords (4,5) == main pair k=1
    __syncthreads();

    // write feat node-major: feat[(n*512+b)*16 + k]
    for (int i = t; i < NB * 16; i += 256) {
        int n = i >> 4, k = i & 15;
        feat[(size_t)((n << 9) + b) * 16 + k] = fs[i];
    }

    // mask = 2-hop expansion: new[row] |= old[col] per edge
    for (int i = t; i < NB; i += 256) m1[i] = m0[i];
    __syncthreads();
    for (int e = t; e < E; e += 256) { int r = ei[e], c = ei[E + e]; if (m0[c]) m1[r] = 1; }
    __syncthreads();
    for (int i = t; i < NB; i += 256) m0[i] = m1[i];
    __syncthreads();
    for (int e = t; e < E; e += 256) { int r = ei[e], c = ei[E + e]; if (m1[c]) m0[r] = 1; }
    __syncthreads();
    for (int i = t; i < NB; i += 256) deg[i] = m0[i];
    __syncthreads();
    for (int e = t; e < E; e += 256) {
        int r = ei[e], c = ei[E + e];
        if (m0[r] && m0[c]) atomicAdd(&deg[c], 1);
    }
    __syncthreads();
    if (t == 0) {
        int cnt = 0;
        for (int n = 0; n < NB; n++) if (m0[n]) {
            loc[n] = cnt;
            mlist[b * 16 + cnt] = n;
            int d = deg[n]; if (d < 1) d = 1;
            mdinv[b * 16 + cnt] = 1.0f / __fsqrt_rn((float)d);
            cnt++;
        }
        mcount[b] = cnt;
    }
    __syncthreads();
    for (int i = t; i < NB; i += 256)
        locg[(size_t)b * NB + i] = m0[i] ? (unsigned char)loc[i] : (unsigned char)255;
    for (int e = t; e < E; e += 256) {
        int r = ei[e], c = ei[E + e];
        if (m0[r] && m0[c]) {
            int s = atomicAdd(&ecnt, 1);
            if (s < 64) medge[b * 64 + s] = loc[r] | (loc[c] << 8);
        }
    }
    __syncthreads();
    if (t == 0) mecnt[b] = ecnt;
}

// ---------------- Kernel T: W1 [256][128] f32 -> W1T [128][256] bf16 ----------------
__global__ __launch_bounds__(256) void kT(const float* __restrict__ W1, short* __restrict__ w1t)
{
    int i = blockIdx.x * 256 + threadIdx.x;      // 32768
    int n = i >> 8, k = i & 255;
    __hip_bfloat16 h = __float2bfloat16(W1[k * 128 + n]);
    w1t[i] = *reinterpret_cast<short*>(&h);
}

// ---------------- Kernel B1: BN1 stats — one block per node ----------------
__global__ __launch_bounds__(256) void kB1(const float* __restrict__ feat,
                                           const float* __restrict__ W0,
                                           const float* __restrict__ b0,
                                           float* __restrict__ sum1, float* __restrict__ sumsq1)
{
    __shared__ float fs[512 * 16];   // 32 KB: all feat rows of this node
    __shared__ float red[8];
    const int n = blockIdx.x, t = threadIdx.x;
    for (int i = t; i < 512 * 16; i += 256) fs[i] = feat[(size_t)n * 8192 + i];
    float w0r[15];
#pragma unroll
    for (int k = 0; k < 15; k++) w0r[k] = W0[k * 256 + t];
    const float bias0 = b0[t];
    __syncthreads();
    float s = 0.f, q = 0.f;
    for (int b = 0; b < 512; b++) {
        float acc = bias0;
#pragma unroll
        for (int k = 0; k < 15; k++) acc = fmaf(fs[b * 16 + k], w0r[k], acc);
        acc = fmaxf(acc, 0.f);
        s += acc; q += acc * acc;
    }
    for (int off = 32; off > 0; off >>= 1) { s += __shfl_down(s, off, 64); q += __shfl_down(q, off, 64); }
    if ((t & 63) == 0) { red[t >> 6] = s; red[4 + (t >> 6)] = q; }
    __syncthreads();
    if (t == 0) {
        sum1[n]   = red[0] + red[1] + red[2] + red[3];
        sumsq1[n] = red[4] + red[5] + red[6] + red[7];
    }
}

// ---------------- Kernel F1: BN1 affine + colsum(W1) ----------------
__global__ __launch_bounds__(512) void kF1(const float* __restrict__ sum1, const float* __restrict__ sumsq1,
                                           const float* __restrict__ g1, const float* __restrict__ be1,
                                           const float* __restrict__ W1,
                                           float* __restrict__ a1, float* __restrict__ b1v,
                                           float* __restrict__ cs1)
{
    const int t = threadIdx.x;
    if (t < NB) {
        const float cnt = 512.f * 256.f;
        float m = sum1[t] / cnt;
        float v = fmaxf(sumsq1[t] / cnt - m * m, 0.f);
        float a = g1[t] / sqrtf(v + 1e-5f);
        a1[t] = a;
        b1v[t] = be1[t] - m * a;
    }
    if (t < 128) {
        float s = 0.f;
        for (int c = 0; c < 256; c++) s += W1[c * 128 + t];
        cs1[t] = s;
    }
}

// ---------------- Kernel B2 (R6): u(f32->bf16 LDS) -> MFMA y=u@W1T -> fold BN1 -> relu
//                  -> BN2 stats -> packed masked store ----------------
// 4 waves: wave w owns N-tile cols [32w,32w+32). 16 K-steps of 32x32x16 bf16 MFMA.
// LDS ~19 KB -> 8 blocks/CU; launch_bounds(256,8) caps VGPR<=64.
__global__ __launch_bounds__(256, 8) void kB2(const float* __restrict__ feat,
                                           const float* __restrict__ W0,
                                           const float* __restrict__ b0,
                                           const short* __restrict__ w1t,
                                           const float* __restrict__ b1,
                                           const float* __restrict__ a1g, const float* __restrict__ b1vg,
                                           const float* __restrict__ cs1,
                                           const unsigned char* __restrict__ locg,
                                           float* __restrict__ xpk,
                                           float* __restrict__ sum2, float* __restrict__ sumsq2)
{
    __shared__ __align__(16) float fT[ROWS * 16];
    __shared__ __align__(16) short uB[ROWS * KSTR];   // bf16 u, row-major [m][k]
    __shared__ float red[8];
    const int t = threadIdx.x;
    const size_t r0 = (size_t)blockIdx.x * ROWS;
    const int node = (int)(r0 >> 9);      // 512 rows per node, 16 blocks/node

    for (int i = t; i < ROWS * 16; i += 256) fT[i] = feat[r0 * 16 + i];
    __syncthreads();

    // phase 2: thread t computes u channel k=t for all 32 rows, writes bf16 to uB[r][t]
    {
        float w0r[15];
#pragma unroll
        for (int k = 0; k < 15; k++) w0r[k] = W0[k * 256 + t];
        const float bias0 = b0[t];
        for (int r = 0; r < ROWS; r++) {
            float acc = bias0;
#pragma unroll
            for (int k = 0; k < 15; k++) acc = fmaf(fT[r * 16 + k], w0r[k], acc);
            __hip_bfloat16 h = __float2bfloat16(fmaxf(acc, 0.f));
            uB[r * KSTR + t] = *reinterpret_cast<short*>(&h);
        }
    }
    __syncthreads();

    // phase 3: MFMA. wave w: cols 32w..32w+31; lane: lm = l&31, quad q = l>>5.
    const int w  = t >> 6;
    const int l  = t & 63;
    const int lm = l & 31;
    const int q  = l >> 5;
    const short* __restrict__ bp = w1t + ((w << 5) + lm) * 256 + (q << 3);
    const short* __restrict__ ap = uB + lm * KSTR + (q << 3);
    f32x16 acc = {0.f, 0.f, 0.f, 0.f, 0.f, 0.f, 0.f, 0.f,
                  0.f, 0.f, 0.f, 0.f, 0.f, 0.f, 0.f, 0.f};
#pragma unroll
    for (int k0 = 0; k0 < 256; k0 += 16) {
        bf16x8 a = *(const bf16x8*)&ap[k0];
        bf16x8 b = *(const bf16x8*)&bp[k0];
        acc = __builtin_amdgcn_mfma_f32_32x32x16_bf16(a, b, acc, 0, 0, 0);
    }

    // epilogue: col n fixed per lane; rows vary per reg.
    // C/D map (verified): col = lane&31, row = (reg&3) + 8*(reg>>2) + 4*(lane>>5)
    const int n_col = (w << 5) + lm;
    const float A = a1g[node];
    const float C = b1vg[node] * cs1[n_col] + b1[n_col];
    float s = 0.f, qq = 0.f;
#pragma unroll
    for (int r = 0; r < 16; r++) {
        int row = (r & 3) + ((r >> 2) << 3) + (q << 2);
        int b   = (int)((r0 + row) & 511);
        float x = fmaxf(fmaf(A, acc[r], C), 0.f);
        s += x; qq += x * x;
        unsigned char lc = locg[(size_t)b * NB + node];
        if (lc != 255) xpk[(size_t)((b << 4) + lc) * 128 + n_col] = x;
    }
    for (int off = 32; off > 0; off >>= 1) { s += __shfl_down(s, off, 64); qq += __shfl_down(qq, off, 64); }
    if (l == 0) { red[w] = s; red[4 + w] = qq; }
    __syncthreads();
    if (t == 0) {
        atomicAdd(&sum2[node],   red[0] + red[1] + red[2] + red[3]);
        atomicAdd(&sumsq2[node], red[4] + red[5] + red[6] + red[7]);
    }
}

// ---------------- Kernel F2: BN2 affine ----------------
__global__ __launch_bounds__(512) void kF2(const float* __restrict__ sum2, const float* __restrict__ sumsq2,
                                           const float* __restrict__ g2, const float* __restrict__ be2,
                                           float* __restrict__ a2, float* __restrict__ b2v)
{
    const int t = threadIdx.x;
    if (t < NB) {
        const float cnt = 512.f * 128.f;
        float m = sum2[t] / cnt;
        float v = fmaxf(sumsq2[t] / cnt - m * m, 0.f);
        float a = g2[t] / sqrtf(v + 1e-5f);
        a2[t] = a;
        b2v[t] = be2[t] - m * a;
    }
}

// ---------------- Kernel E: masked 2-layer GCN + mean, per batch ----------------
__global__ __launch_bounds__(128) void kE(const float* __restrict__ xpk,
                                          const float* __restrict__ a2, const float* __restrict__ b2v,
                                          const float* __restrict__ Wc,
                                          const float* __restrict__ bc,
                                          const int* __restrict__ mcount, const int* __restrict__ mlist,
                                          const float* __restrict__ mdinv, const int* __restrict__ mecnt,
                                          const int* __restrict__ medge,
                                          float* __restrict__ out)
{
    __shared__ float xs[13 * 128];
    __shared__ float hs[13 * 128];
    __shared__ float dv[13];
    __shared__ int   ml[13];
    __shared__ int   eg[64];
    __shared__ int   Ms, Es;
    const int b = blockIdx.x, j = threadIdx.x;
    if (j == 0) { Ms = mcount[b]; Es = mecnt[b]; }
    __syncthreads();
    const int M = Ms, E2 = (Es > 64) ? 64 : Es;
    if (j < 13) {
        if (j < M) { ml[j] = mlist[b * 16 + j]; dv[j] = mdinv[b * 16 + j]; }
        else dv[j] = 0.f;
    }
    for (int e = j; e < E2; e += 128) eg[e] = medge[b * 64 + e];
    __syncthreads();
    // x = a2*x_pre + b2v at masked nodes
    for (int m = 0; m < 13; m++) {
        float v = 0.f;
        if (m < M) {
            int nn = ml[m];
            v = fmaf(a2[nn], xpk[(size_t)((b << 4) + m) * 128 + j], b2v[nn]);
        }
        xs[m * 128 + j] = v;
    }
    __syncthreads();

    for (int it = 0; it < 2; it++) {
        float acc[13];
#pragma unroll
        for (int m = 0; m < 13; m++) acc[m] = 0.f;
        const float* W = Wc + it * 16384;
        for (int c = 0; c < 128; c++) {
            float w = W[c * 128 + j];
#pragma unroll
            for (int m = 0; m < 13; m++) acc[m] = fmaf(xs[m * 128 + c], w, acc[m]);
        }
        __syncthreads();
#pragma unroll
        for (int m = 0; m < 13; m++) hs[m * 128 + j] = acc[m];
#pragma unroll
        for (int m = 0; m < 13; m++) xs[m * 128 + j] = dv[m] * dv[m] * acc[m];
        for (int e = 0; e < E2; e++) {
            int pr = eg[e] & 255, pc = eg[e] >> 8;
            xs[pc * 128 + j] += dv[pr] * dv[pc] * hs[pr * 128 + j];
        }
        float bcv = bc[it * 128 + j];
        for (int m = 0; m < M; m++) xs[m * 128 + j] += bcv;
        __syncthreads();
    }
    float sall = 0.f;
    for (int m = 0; m < M; m++) sall += xs[m * 128 + j];
    out[b * 128 + j] = sall / (float)M;
}

extern "C" void kernel_launch(void* const* d_in, const int* in_sizes, int n_in,
                              void* d_out, int out_size, void* d_ws, size_t ws_size,
                              hipStream_t stream)
{
    const float* agvs  = (const float*)d_in[0];
    const float* nodes = (const float*)d_in[1];
    const int*   ei    = (const int*)d_in[2];
    const float* W0    = (const float*)d_in[3];
    const float* b0    = (const float*)d_in[4];
    const float* g1    = (const float*)d_in[5];
    const float* be1   = (const float*)d_in[6];
    const float* W1    = (const float*)d_in[7];
    const float* b1    = (const float*)d_in[8];
    const float* g2    = (const float*)d_in[9];
    const float* be2   = (const float*)d_in[10];
    const float* Wc    = (const float*)d_in[11];
    const float* bc    = (const float*)d_in[12];
    const int E = in_sizes[2] / 2;

    char* ws = (char*)d_ws;
    float*          feat   = (float*)(ws + O_FEAT);
    float*          xpk    = (float*)(ws + O_XPK);
    float*          sum1   = (float*)(ws + O_STATS);
    float*          sumsq1 = sum1 + NB;
    float*          sum2   = sum1 + 2 * NB;
    float*          sumsq2 = sum1 + 3 * NB;
    float*          a1     = (float*)(ws + O_AB);
    float*          b1v    = a1 + NB;
    float*          a2     = a1 + 2 * NB;
    float*          b2v    = a1 + 3 * NB;
    float*          cs1    = (float*)(ws + O_CS1);
    int*            mcount = (int*)(ws + O_MCNT);
    int*            mlist  = (int*)(ws + O_MLIST);
    float*          mdinv  = (float*)(ws + O_MDINV);
    int*            mecnt  = (int*)(ws + O_MECNT);
    int*            medge  = (int*)(ws + O_MEDGE);
    unsigned char*  locg   = (unsigned char*)(ws + O_LOCG);
    short*          w1t    = (short*)(ws + O_W1T);

    hipMemsetAsync(ws + O_STATS, 0, 4 * NB * sizeof(float), stream);

    kT<<<128, 256, 0, stream>>>(W1, w1t);
    kA<<<BB, 256, 0, stream>>>(agvs, nodes, ei, E, feat, mcount, mlist, mdinv, mecnt, medge, locg);
    kB1<<<NB, 256, 0, stream>>>(feat, W0, b0, sum1, sumsq1);
    kF1<<<1, 512, 0, stream>>>(sum1, sumsq1, g1, be1, W1, a1, b1v, cs1);
    kB2<<<(NB * BB) / ROWS, 256, 0, stream>>>(feat, W0, b0, w1t, b1, a1, b1v, cs1, locg,
                                              xpk, sum2, sumsq2);
    kF2<<<1, 512, 0, stream>>>(sum2, sumsq2, g2, be2, a2, b2v);
    kE<<<BB, 128, 0, stream>>>(xpk, a2, b2v, Wc, bc, mcount, mlist, mdinv, mecnt, medge,
                               (float*)d_out);
}